// Round 10
// baseline (136.339 us; speedup 1.0000x reference)
//
#include <hip/hip_runtime.h>

#define NF 8
#define BSHIFT 8
#define BNODES 256          // nodes per bucket = 1 << BSHIFT
#define MAXNB 512           // max buckets supported (n_nodes <= 131072)
#define NBLK 512            // blocks for hist/scatter
#define TPBW 1024           // threads for hist/scatter
#define TPB 256
#define TPR 512             // threads for reduce (2 per node)
#define CHUNK 4096          // edges per sort tile
#define SPLIT 8             // slices per bucket (slice ~2048 records)
#define LSLICE 2560         // LDS-resident slice capacity (records); mean ~2048
#define KPT 5               // LSLICE / TPR

// P0: transpose q[f][n] -> qT[n][f]; also zero the global overflow accumulator.
__global__ void k_transpose(const float* __restrict__ q, float* __restrict__ qT,
                            float* __restrict__ govf, int n_nodes) {
    int n = blockIdx.x * blockDim.x + threadIdx.x;
    if (n >= n_nodes) return;
    float4 a, b;
    a.x = q[0 * n_nodes + n]; a.y = q[1 * n_nodes + n];
    a.z = q[2 * n_nodes + n]; a.w = q[3 * n_nodes + n];
    b.x = q[4 * n_nodes + n]; b.y = q[5 * n_nodes + n];
    b.z = q[6 * n_nodes + n]; b.w = q[7 * n_nodes + n];
    float4* dst = reinterpret_cast<float4*>(qT + (size_t)n * NF);
    dst[0] = a; dst[1] = b;
    float* o = govf + (size_t)n * 9;
#pragma unroll
    for (int k = 0; k < 9; ++k) o[k] = 0.f;
}

// P1: PER-TILE bucket histogram, TILE-MAJOR: cnt[t*nb + bi] (coalesced writes)
__global__ __launch_bounds__(TPBW) void k_hist(const int* __restrict__ receivers, int n_edges,
                                               int nb, int tiles, unsigned* __restrict__ cnt) {
    __shared__ unsigned hist[MAXNB];
    for (int t = blockIdx.x; t < tiles; t += gridDim.x) {
        for (int i = threadIdx.x; i < nb; i += blockDim.x) hist[i] = 0;
        __syncthreads();
        int start = t * CHUNK;
        int end = min(start + CHUNK, n_edges);
        int e4 = start + threadIdx.x * 4;
        if (e4 + 3 < end) {
            int4 r4 = *reinterpret_cast<const int4*>(receivers + e4);
            atomicAdd(&hist[r4.x >> BSHIFT], 1u);
            atomicAdd(&hist[r4.y >> BSHIFT], 1u);
            atomicAdd(&hist[r4.z >> BSHIFT], 1u);
            atomicAdd(&hist[r4.w >> BSHIFT], 1u);
        } else {
            for (int e = e4; e < end; ++e)
                atomicAdd(&hist[receivers[e] >> BSHIFT], 1u);
        }
        __syncthreads();
        for (int i = threadIdx.x; i < nb; i += blockDim.x)
            cnt[(size_t)t * nb + i] = hist[i];
        __syncthreads();
    }
}

// P2a: one WAVE per bucket: exclusive scan of the bucket's per-tile counts -> rel.
__global__ void k_scan1(const unsigned* __restrict__ cnt, unsigned* __restrict__ rel,
                        int nb, int tiles, unsigned* __restrict__ tot) {
    int wave = (blockIdx.x * blockDim.x + threadIdx.x) >> 6;
    int lane = threadIdx.x & 63;
    if (wave >= nb) return;
    unsigned carry = 0;
    for (int base = 0; base < tiles; base += 64) {
        int t = base + lane;
        unsigned v = (t < tiles) ? cnt[(size_t)t * nb + wave] : 0u;
        unsigned x = v;
        for (int d = 1; d < 64; d <<= 1) {
            unsigned y = __shfl_up(x, d, 64);
            if (lane >= d) x += y;
        }
        if (t < tiles) rel[(size_t)t * nb + wave] = carry + x - v;
        carry += __shfl(x, 63, 64);
    }
    if (lane == 0) tot[wave] = carry;
}

// P2b: exclusive scan over nb bucket totals. Single block, nb<=512.
__global__ void k_scan2(const unsigned* __restrict__ tot, int nb,
                        unsigned* __restrict__ bucket_base) {
    __shared__ unsigned a[MAXNB];
    __shared__ unsigned b[MAXNB];
    int t = threadIdx.x;
    unsigned* src = a;
    unsigned* dst = b;
    if (t < nb) src[t] = tot[t];
    __syncthreads();
    for (int d = 1; d < nb; d <<= 1) {
        if (t < nb) dst[t] = (t >= d) ? src[t] + src[t - d] : src[t];
        __syncthreads();
        unsigned* tmp = src; src = dst; dst = tmp;
    }
    if (t < nb) bucket_base[t + 1] = src[t];
    if (t == 0) bucket_base[0] = 0;
}

// P3: LDS counting-sort scatter. Per tile: sort records into LDS, then emit
// run-coalesced sequential writes. 1 LDS atomic per edge.
__global__ __launch_bounds__(TPBW) void k_scatter(
        const float* __restrict__ edges, const int* __restrict__ senders,
        const int* __restrict__ receivers, int n_edges, int nb, int tiles,
        const unsigned* __restrict__ cnt, const unsigned* __restrict__ rel,
        const unsigned* __restrict__ bucket_base, uint2* __restrict__ rec) {
    __shared__ uint2 lrec[CHUNK];            // 32 KB
    __shared__ unsigned short lbkt[CHUNK];   // 8 KB
    __shared__ unsigned gbase[MAXNB];        // 2 KB
    __shared__ unsigned lbase[MAXNB + 1];    // 2 KB
    __shared__ unsigned lcur[MAXNB];         // 2 KB

    for (int t = blockIdx.x; t < tiles; t += gridDim.x) {
        for (int bi = threadIdx.x; bi < nb; bi += blockDim.x) {
            gbase[bi] = bucket_base[bi] + rel[(size_t)t * nb + bi];
            lcur[bi] = 0;
        }
        __syncthreads();
        if (threadIdx.x < 64) {
            int lane = threadIdx.x;
            unsigned carry = 0;
            for (int base = 0; base < nb; base += 64) {
                int bi = base + lane;
                unsigned v = (bi < nb) ? cnt[(size_t)t * nb + bi] : 0u;
                unsigned x = v;
                for (int d = 1; d < 64; d <<= 1) {
                    unsigned y = __shfl_up(x, d, 64);
                    if (lane >= d) x += y;
                }
                if (bi < nb) lbase[bi] = carry + x - v;
                carry += __shfl(x, 63, 64);
            }
            if (lane == 0) lbase[nb] = carry;
        }
        __syncthreads();

        int start = t * CHUNK;
        int n = min(CHUNK, n_edges - start);

        for (int i = threadIdx.x; i < n; i += blockDim.x) {
            int e = start + i;
            int s = senders[e];
            int r = receivers[e];
            float ev = edges[e];
            int bkt = r >> BSHIFT;
            unsigned p = atomicAdd(&lcur[bkt], 1u);
            unsigned slot = lbase[bkt] + p;
            uint2 rc;
            rc.x = ((unsigned)(r & (BNODES - 1)) << 17) | (unsigned)s;
            rc.y = __float_as_uint(ev);
            lrec[slot] = rc;
            lbkt[slot] = (unsigned short)bkt;
        }
        __syncthreads();

        for (int j = threadIdx.x; j < n; j += blockDim.x) {
            unsigned bkt = lbkt[j];
            unsigned gaddr = gbase[bkt] + ((unsigned)j - lbase[bkt]);
            rec[gaddr] = lrec[j];
        }
        __syncthreads();
    }
}

// P4: counting-sort reduce. Phase a: records -> registers + count (1 LDS atomic).
// Phase b: scan 256 counts. Phase c: write records to SORTED LDS position.
// Pass 2: per-node contiguous LDS reads with 4-DEEP BATCHED qT gathers (latency
// hiding), register accumulation, pair-combine via shfl_xor.
__global__ __launch_bounds__(TPR) void k_reduce_slot(
        const uint2* __restrict__ rec, const unsigned* __restrict__ bucket_base,
        const float* __restrict__ qT, float* __restrict__ part,
        float* __restrict__ govf, int n_nodes) {
    __shared__ uint2 srec[LSLICE];       // 20 KB sorted records
    __shared__ unsigned cur[BNODES];     // per-node counts
    __shared__ unsigned nbase[BNODES];   // exclusive scan of counts
    int t = threadIdx.x;
    if (t < BNODES) cur[t] = 0;
    __syncthreads();

    int bkt = blockIdx.x / SPLIT;
    int s   = blockIdx.x % SPLIT;
    unsigned e0 = bucket_base[bkt], e1 = bucket_base[bkt + 1];
    unsigned len = e1 - e0;
    unsigned a0 = e0 + (unsigned)(((unsigned long long)len * s) / SPLIT);
    unsigned a1 = e0 + (unsigned)(((unsigned long long)len * (s + 1)) / SPLIT);
    unsigned slice = a1 - a0;
    unsigned lds_n = slice < LSLICE ? slice : LSLICE;

    // phase a: load to registers, count via LDS atomic, remember position
    uint2    r0[KPT];
    unsigned p0[KPT];
#pragma unroll
    for (int k = 0; k < KPT; ++k) {
        unsigned i = (unsigned)t + (unsigned)k * TPR;
        p0[k] = 0xFFFFFFFFu;
        if (i < lds_n) {
            uint2 rc = rec[a0 + i];
            r0[k] = rc;
            p0[k] = atomicAdd(&cur[rc.x >> 17], 1u);
        }
    }
    // slice overflow (essentially never): exact accumulate via global atomics
    for (unsigned i = LSLICE + t; i < slice; i += TPR) {
        uint2 rc = rec[a0 + i];
        unsigned snd = rc.x & 0x1FFFFu;
        unsigned rl = rc.x >> 17;
        float ev = __uint_as_float(rc.y);
        const float4* qs = reinterpret_cast<const float4*>(qT + (size_t)snd * NF);
        float4 q0 = qs[0];
        float4 q1 = qs[1];
        float* a = govf + ((size_t)bkt * BNODES + rl) * 9;
        atomicAdd(a + 0, q0.x); atomicAdd(a + 1, q0.y);
        atomicAdd(a + 2, q0.z); atomicAdd(a + 3, q0.w);
        atomicAdd(a + 4, q1.x); atomicAdd(a + 5, q1.y);
        atomicAdd(a + 6, q1.z); atomicAdd(a + 7, q1.w);
        atomicAdd(a + 8, ev);
    }
    __syncthreads();

    // phase b: exclusive scan of cur[256] -> nbase (first wave, 4 chunks w/ carry)
    if (t < 64) {
        unsigned carry = 0;
        for (int c = 0; c < BNODES; c += 64) {
            unsigned v = cur[c + t];
            unsigned x = v;
            for (int d = 1; d < 64; d <<= 1) {
                unsigned y = __shfl_up(x, d, 64);
                if (t >= d) x += y;
            }
            nbase[c + t] = carry + x - v;
            carry += __shfl(x, 63, 64);
        }
    }
    __syncthreads();

    // phase c: place register-held records at sorted LDS positions
#pragma unroll
    for (int k = 0; k < KPT; ++k) {
        if (p0[k] != 0xFFFFFFFFu) {
            unsigned rl = r0[k].x >> 17;
            srec[nbase[rl] + p0[k]] = r0[k];
        }
    }
    __syncthreads();

    // pass 2: threads (2n, 2n+1) own node n; contiguous run, parity-split,
    // 4-deep batched gathers so all 8 dwordx4 loads are in flight together.
    int node = t >> 1;
    int parity = t & 1;
    unsigned nb0 = nbase[node];
    unsigned ncnt = cur[node];
    float m[9];
#pragma unroll
    for (int k = 0; k < 9; ++k) m[k] = 0.f;
    unsigned j = parity;
    for (; j + 6 < ncnt; j += 8) {
        uint2 rc0 = srec[nb0 + j];
        uint2 rc1 = srec[nb0 + j + 2];
        uint2 rc2 = srec[nb0 + j + 4];
        uint2 rc3 = srec[nb0 + j + 6];
        const float4* g0 = reinterpret_cast<const float4*>(qT + (size_t)(rc0.x & 0x1FFFFu) * NF);
        const float4* g1 = reinterpret_cast<const float4*>(qT + (size_t)(rc1.x & 0x1FFFFu) * NF);
        const float4* g2 = reinterpret_cast<const float4*>(qT + (size_t)(rc2.x & 0x1FFFFu) * NF);
        const float4* g3 = reinterpret_cast<const float4*>(qT + (size_t)(rc3.x & 0x1FFFFu) * NF);
        float4 a0v = g0[0], b0v = g0[1];
        float4 a1v = g1[0], b1v = g1[1];
        float4 a2v = g2[0], b2v = g2[1];
        float4 a3v = g3[0], b3v = g3[1];
        m[0] += (a0v.x + a1v.x) + (a2v.x + a3v.x);
        m[1] += (a0v.y + a1v.y) + (a2v.y + a3v.y);
        m[2] += (a0v.z + a1v.z) + (a2v.z + a3v.z);
        m[3] += (a0v.w + a1v.w) + (a2v.w + a3v.w);
        m[4] += (b0v.x + b1v.x) + (b2v.x + b3v.x);
        m[5] += (b0v.y + b1v.y) + (b2v.y + b3v.y);
        m[6] += (b0v.z + b1v.z) + (b2v.z + b3v.z);
        m[7] += (b0v.w + b1v.w) + (b2v.w + b3v.w);
        m[8] += (__uint_as_float(rc0.y) + __uint_as_float(rc1.y))
              + (__uint_as_float(rc2.y) + __uint_as_float(rc3.y));
    }
    for (; j < ncnt; j += 2) {
        uint2 rc = srec[nb0 + j];
        const float4* g = reinterpret_cast<const float4*>(qT + (size_t)(rc.x & 0x1FFFFu) * NF);
        float4 av = g[0], bv = g[1];
        m[0] += av.x; m[1] += av.y; m[2] += av.z; m[3] += av.w;
        m[4] += bv.x; m[5] += bv.y; m[6] += bv.z; m[7] += bv.w;
        m[8] += __uint_as_float(rc.y);
    }

    // pair-combine across (2n, 2n+1) via shuffle; even lane writes the partial
#pragma unroll
    for (int k = 0; k < 9; ++k) m[k] += __shfl_xor(m[k], 1, 64);
    if (parity == 0) {
        float* dst = part + (size_t)blockIdx.x * (BNODES * 9) + (size_t)node * 9;
#pragma unroll
        for (int k = 0; k < 9; ++k) dst[k] = m[k];
    }
}

// P5: sum SPLIT partials per node (+ global overflow), fused finalize.
__global__ void k_finalize2(const float* __restrict__ part, const float* __restrict__ govf,
                            const float* __restrict__ q,
                            const float* __restrict__ dtp, const float* __restrict__ w_self,
                            const float* __restrict__ w_msg, const float* __restrict__ w_edge,
                            const float* __restrict__ bv, float* __restrict__ out,
                            int split, int n_nodes) {
    int n = blockIdx.x * blockDim.x + threadIdx.x;
    if (n >= n_nodes) return;
    int bkt = n >> BSHIFT;
    int rl = n & (BNODES - 1);
    float m[9];
#pragma unroll
    for (int f = 0; f < 9; ++f) m[f] = govf[(size_t)n * 9 + f];
    for (int s = 0; s < split; ++s) {
        const float* p = part + ((size_t)(bkt * split + s) * BNODES + rl) * 9;
#pragma unroll
        for (int f = 0; f < 9; ++f) m[f] += p[f];
    }
    float dtv = dtp[0];
    float evs = m[8];
#pragma unroll
    for (int f = 0; f < NF; ++f) {
        float msg = m[f] + w_edge[f] * evs;
        out[(size_t)f * n_nodes + n] =
            dtv * (w_self[f] * q[(size_t)f * n_nodes + n] + w_msg[f] * msg + bv[f]);
    }
}

// P4-fused fallback (one block per bucket; used only if part buffer doesn't fit)
__global__ void k_reduce_fused(const uint2* __restrict__ rec,
                               const unsigned* __restrict__ bucket_base,
                               const float* __restrict__ qT, const float* __restrict__ q,
                               const float* __restrict__ dtp, const float* __restrict__ w_self,
                               const float* __restrict__ w_msg, const float* __restrict__ w_edge,
                               const float* __restrict__ bv, float* __restrict__ out,
                               int n_nodes) {
    __shared__ float acc[BNODES * 9];
    for (int i = threadIdx.x; i < BNODES * 9; i += blockDim.x) acc[i] = 0.f;
    __syncthreads();
    int bkt = blockIdx.x;
    unsigned e0 = bucket_base[bkt], e1 = bucket_base[bkt + 1];
    for (unsigned e = e0 + threadIdx.x; e < e1; e += blockDim.x) {
        uint2 rc = rec[e];
        unsigned snd = rc.x & 0x1FFFFu;
        unsigned rl = rc.x >> 17;
        float ev = __uint_as_float(rc.y);
        const float4* qs = reinterpret_cast<const float4*>(qT + (size_t)snd * NF);
        float4 q0 = qs[0];
        float4 q1 = qs[1];
        float* a = &acc[rl * 9];
        atomicAdd(a + 0, q0.x); atomicAdd(a + 1, q0.y);
        atomicAdd(a + 2, q0.z); atomicAdd(a + 3, q0.w);
        atomicAdd(a + 4, q1.x); atomicAdd(a + 5, q1.y);
        atomicAdd(a + 6, q1.z); atomicAdd(a + 7, q1.w);
        atomicAdd(a + 8, ev);
    }
    __syncthreads();
    int n = bkt * BNODES + threadIdx.x;
    if (n < n_nodes) {
        float dtv = dtp[0];
        float evs = acc[threadIdx.x * 9 + 8];
#pragma unroll
        for (int f = 0; f < NF; ++f) {
            float msg = acc[threadIdx.x * 9 + f] + w_edge[f] * evs;
            out[(size_t)f * n_nodes + n] =
                dtv * (w_self[f] * q[(size_t)f * n_nodes + n] + w_msg[f] * msg + bv[f]);
        }
    }
}

// ---------- last-resort fallback (global atomics) ----------
__global__ void k_transpose_zero(const float* __restrict__ q, float* __restrict__ qT,
                                 float* __restrict__ msgT, int n_nodes) {
    int n = blockIdx.x * blockDim.x + threadIdx.x;
    if (n >= n_nodes) return;
    float v[NF];
#pragma unroll
    for (int f = 0; f < NF; ++f) v[f] = q[f * n_nodes + n];
    float4* dst = reinterpret_cast<float4*>(qT + (size_t)n * NF);
    dst[0] = make_float4(v[0], v[1], v[2], v[3]);
    dst[1] = make_float4(v[4], v[5], v[6], v[7]);
    float4 z = make_float4(0.f, 0.f, 0.f, 0.f);
    float4* m = reinterpret_cast<float4*>(msgT + (size_t)n * NF);
    m[0] = z; m[1] = z;
}

__global__ void k_edge_scatter(const float* __restrict__ edges, const int* __restrict__ senders,
                               const int* __restrict__ receivers, const float* __restrict__ qT,
                               float* __restrict__ msgT, const float* __restrict__ w_edge,
                               int n_edges) {
    float we[NF];
#pragma unroll
    for (int f = 0; f < NF; ++f) we[f] = w_edge[f];
    int idx = blockIdx.x * blockDim.x + threadIdx.x;
    int stride = gridDim.x * blockDim.x;
    for (int e = idx; e < n_edges; e += stride) {
        int s = senders[e];
        int r = receivers[e];
        float ev = edges[e];
        const float4* qs = reinterpret_cast<const float4*>(qT + (size_t)s * NF);
        float4 q0 = qs[0];
        float4 q1 = qs[1];
        float* m = msgT + (size_t)r * NF;
        atomicAdd(m + 0, q0.x + we[0] * ev);
        atomicAdd(m + 1, q0.y + we[1] * ev);
        atomicAdd(m + 2, q0.z + we[2] * ev);
        atomicAdd(m + 3, q0.w + we[3] * ev);
        atomicAdd(m + 4, q1.x + we[4] * ev);
        atomicAdd(m + 5, q1.y + we[5] * ev);
        atomicAdd(m + 6, q1.z + we[6] * ev);
        atomicAdd(m + 7, q1.w + we[7] * ev);
    }
}

__global__ void k_finalize(const float* __restrict__ q, const float* __restrict__ msgT,
                           const float* __restrict__ dt, const float* __restrict__ w_self,
                           const float* __restrict__ w_msg, const float* __restrict__ b,
                           float* __restrict__ out, int n_nodes) {
    int n = blockIdx.x * blockDim.x + threadIdx.x;
    if (n >= n_nodes) return;
    float dtv = dt[0];
    const float4* m4 = reinterpret_cast<const float4*>(msgT + (size_t)n * NF);
    float4 m0 = m4[0];
    float4 m1 = m4[1];
    float mv[NF] = {m0.x, m0.y, m0.z, m0.w, m1.x, m1.y, m1.z, m1.w};
#pragma unroll
    for (int f = 0; f < NF; ++f) {
        out[f * n_nodes + n] = dtv * (w_self[f] * q[f * n_nodes + n] + w_msg[f] * mv[f] + b[f]);
    }
}

// ---------------- launch ----------------
extern "C" void kernel_launch(void* const* d_in, const int* in_sizes, int n_in,
                              void* d_out, int out_size, void* d_ws, size_t ws_size,
                              hipStream_t stream) {
    const float* q         = (const float*)d_in[0];
    const float* edges     = (const float*)d_in[1];
    const int*   senders   = (const int*)d_in[2];
    const int*   receivers = (const int*)d_in[3];
    const float* dt        = (const float*)d_in[4];
    const float* w_self    = (const float*)d_in[5];
    const float* w_msg     = (const float*)d_in[6];
    const float* w_edge    = (const float*)d_in[7];
    const float* b         = (const float*)d_in[8];
    float* out = (float*)d_out;

    const int n_nodes = in_sizes[0] / NF;   // 100000
    const int n_edges = in_sizes[2];        // 6400000
    const int nb = (n_nodes + BNODES - 1) >> BSHIFT;
    const int tiles = (n_edges + CHUNK - 1) / CHUNK;

    size_t rec_bytes   = (size_t)n_edges * 8;
    size_t qT_bytes    = (size_t)n_nodes * NF * 4;
    size_t cnt_bytes   = (size_t)nb * tiles * 4;
    size_t tot_bytes   = (size_t)nb * 4;
    size_t bbase_bytes = (size_t)(nb + 1) * 4;
    size_t govf_bytes  = (size_t)nb * BNODES * 9 * 4;
    size_t fixed = rec_bytes + qT_bytes + 2 * cnt_bytes + tot_bytes + bbase_bytes
                 + govf_bytes + 1024;
    size_t part_bytes = (size_t)SPLIT * nb * BNODES * 9 * 4;

    bool sorted_ok = (n_nodes <= 131072) && (nb <= MAXNB) && (fixed <= ws_size);
    bool slot_ok = sorted_ok && (fixed + part_bytes <= ws_size);

    if (slot_ok) {
        char* p = (char*)d_ws;
        uint2*    rec         = (uint2*)p;    p += rec_bytes;
        float*    qT          = (float*)p;    p += qT_bytes;
        unsigned* cnt         = (unsigned*)p; p += cnt_bytes;
        unsigned* rel         = (unsigned*)p; p += cnt_bytes;
        unsigned* tot         = (unsigned*)p; p += tot_bytes;
        unsigned* bucket_base = (unsigned*)p; p += bbase_bytes;
        float*    govf        = (float*)p;    p += govf_bytes;
        float*    part        = (float*)(((uintptr_t)p + 255) & ~(uintptr_t)255);

        k_transpose<<<(n_nodes + TPB - 1) / TPB, TPB, 0, stream>>>(q, qT, govf, n_nodes);
        k_hist<<<NBLK, TPBW, 0, stream>>>(receivers, n_edges, nb, tiles, cnt);
        k_scan1<<<(nb + 3) / 4, TPB, 0, stream>>>(cnt, rel, nb, tiles, tot);
        k_scan2<<<1, 512, 0, stream>>>(tot, nb, bucket_base);
        k_scatter<<<NBLK, TPBW, 0, stream>>>(edges, senders, receivers, n_edges, nb, tiles,
                                             cnt, rel, bucket_base, rec);
        k_reduce_slot<<<nb * SPLIT, TPR, 0, stream>>>(rec, bucket_base, qT, part,
                                                      govf, n_nodes);
        k_finalize2<<<(n_nodes + TPB - 1) / TPB, TPB, 0, stream>>>(
            part, govf, q, dt, w_self, w_msg, w_edge, b, out, SPLIT, n_nodes);
    } else if (sorted_ok) {
        char* p = (char*)d_ws;
        uint2*    rec         = (uint2*)p;    p += rec_bytes;
        float*    qT          = (float*)p;    p += qT_bytes;
        unsigned* cnt         = (unsigned*)p; p += cnt_bytes;
        unsigned* rel         = (unsigned*)p; p += cnt_bytes;
        unsigned* tot         = (unsigned*)p; p += tot_bytes;
        unsigned* bucket_base = (unsigned*)p; p += bbase_bytes;
        float*    govf        = (float*)p;

        k_transpose<<<(n_nodes + TPB - 1) / TPB, TPB, 0, stream>>>(q, qT, govf, n_nodes);
        k_hist<<<NBLK, TPBW, 0, stream>>>(receivers, n_edges, nb, tiles, cnt);
        k_scan1<<<(nb + 3) / 4, TPB, 0, stream>>>(cnt, rel, nb, tiles, tot);
        k_scan2<<<1, 512, 0, stream>>>(tot, nb, bucket_base);
        k_scatter<<<NBLK, TPBW, 0, stream>>>(edges, senders, receivers, n_edges, nb, tiles,
                                             cnt, rel, bucket_base, rec);
        k_reduce_fused<<<nb, BNODES, 0, stream>>>(rec, bucket_base, qT, q, dt, w_self,
                                                  w_msg, w_edge, b, out, n_nodes);
    } else {
        float* qT   = (float*)d_ws;
        float* msgT = qT + (size_t)n_nodes * NF;
        k_transpose_zero<<<(n_nodes + TPB - 1) / TPB, TPB, 0, stream>>>(q, qT, msgT, n_nodes);
        k_edge_scatter<<<3072, TPB, 0, stream>>>(edges, senders, receivers, qT, msgT,
                                                 w_edge, n_edges);
        k_finalize<<<(n_nodes + TPB - 1) / TPB, TPB, 0, stream>>>(q, msgT, dt, w_self, w_msg,
                                                                  b, out, n_nodes);
    }
}

// Round 11
// 111.261 us; speedup vs baseline: 1.2254x; 1.2254x over previous
//
#include <hip/hip_runtime.h>

#define NF 8
#define BSHIFT 8
#define BNODES 256          // nodes per bucket = 1 << BSHIFT
#define MAXNB 512           // max buckets supported (n_nodes <= 131072)
#define TPB 256
#define TPR 512             // threads for reduce (2 per node)
#define TPBF 1024           // threads for fused scatter
#define CHUNKF 12288        // edges per fused-scatter block (~128 KB LDS)
#define CAPB 17408          // per-bucket region capacity (mean 16368 + 8 sigma)
#define SPLIT 8             // slices per bucket (slice ~2048 records)
#define CAP 24              // slots per node per block-slice
#define IDXSTR 26           // padded stride -> conflict-free u16 reads
#define LSLICE 2560         // LDS-resident slice capacity (records)

// P0: transpose q[f][n] -> qT[n][f]; zero govf and the global bucket cursors.
__global__ void k_transpose(const float* __restrict__ q, float* __restrict__ qT,
                            float* __restrict__ govf, unsigned* __restrict__ gcur,
                            int n_nodes, int nb) {
    int n = blockIdx.x * blockDim.x + threadIdx.x;
    if (n < nb) gcur[n] = 0u;
    if (n >= n_nodes) return;
    float4 a, b;
    a.x = q[0 * n_nodes + n]; a.y = q[1 * n_nodes + n];
    a.z = q[2 * n_nodes + n]; a.w = q[3 * n_nodes + n];
    b.x = q[4 * n_nodes + n]; b.y = q[5 * n_nodes + n];
    b.z = q[6 * n_nodes + n]; b.w = q[7 * n_nodes + n];
    float4* dst = reinterpret_cast<float4*>(qT + (size_t)n * NF);
    dst[0] = a; dst[1] = b;
    float* o = govf + (size_t)n * 9;
#pragma unroll
    for (int k = 0; k < 9; ++k) o[k] = 0.f;
}

// P1 (fused): per-block {LDS hist -> global reservation -> LDS counting sort ->
// run-coalesced write-out into fixed-capacity bucket regions}. One kernel
// replaces hist + scan1 + scan2 + scatter. 1 LDS atomic/edge for the sort,
// nb global atomics/block for the reservation.
__global__ __launch_bounds__(TPBF) void k_scatter_fused(
        const float* __restrict__ edges, const int* __restrict__ senders,
        const int* __restrict__ receivers, int n_edges, int nb,
        unsigned* __restrict__ gcur, const float* __restrict__ qT,
        float* __restrict__ govf, uint2* __restrict__ rec) {
    __shared__ uint2 lrec[CHUNKF];            // 96 KB
    __shared__ unsigned short lbkt[CHUNKF];   // 24 KB
    __shared__ unsigned hist[MAXNB];          // 2 KB
    __shared__ unsigned lbase[MAXNB];         // 2 KB
    __shared__ unsigned gbase[MAXNB];         // 2 KB
    __shared__ unsigned lcur[MAXNB];          // 2 KB

    int start = blockIdx.x * CHUNKF;
    int end = min(start + CHUNKF, n_edges);
    int n = end - start;
    if (n <= 0) return;

    for (int i = threadIdx.x; i < nb; i += TPBF) { hist[i] = 0u; lcur[i] = 0u; }
    __syncthreads();

    // pass A: histogram this chunk (receivers stream; stays hot in L2)
    for (int i = threadIdx.x; i < n; i += TPBF)
        atomicAdd(&hist[receivers[start + i] >> BSHIFT], 1u);
    __syncthreads();

    // reserve region space per bucket (global atomic, L2-resident counters)
    if (threadIdx.x < (unsigned)nb)
        gbase[threadIdx.x] = atomicAdd(&gcur[threadIdx.x], hist[threadIdx.x]);
    // wave 0: exclusive scan of hist -> lbase (chunks of 64 with carry)
    if (threadIdx.x < 64) {
        int lane = threadIdx.x;
        unsigned carry = 0;
        for (int base = 0; base < nb; base += 64) {
            int bi = base + lane;
            unsigned v = (bi < nb) ? hist[bi] : 0u;
            unsigned x = v;
            for (int d = 1; d < 64; d <<= 1) {
                unsigned y = __shfl_up(x, d, 64);
                if (lane >= d) x += y;
            }
            if (bi < nb) lbase[bi] = carry + x - v;
            carry += __shfl(x, 63, 64);
        }
    }
    __syncthreads();

    // pass B: place into tile-local sorted LDS position (receivers re-read from L2)
    for (int i = threadIdx.x; i < n; i += TPBF) {
        int e = start + i;
        int s = senders[e];
        int r = receivers[e];
        float ev = edges[e];
        int bkt = r >> BSHIFT;
        unsigned p = atomicAdd(&lcur[bkt], 1u);
        unsigned slot = lbase[bkt] + p;
        uint2 rc;
        rc.x = ((unsigned)(r & (BNODES - 1)) << 17) | (unsigned)s;
        rc.y = __float_as_uint(ev);
        lrec[slot] = rc;
        lbkt[slot] = (unsigned short)bkt;
    }
    __syncthreads();

    // write-out: consecutive threads -> consecutive addresses per run
    for (int j = threadIdx.x; j < n; j += TPBF) {
        unsigned bkt = lbkt[j];
        uint2 rc = lrec[j];
        unsigned off = gbase[bkt] + ((unsigned)j - lbase[bkt]);
        if (off < CAPB) {
            rec[(size_t)bkt * CAPB + off] = rc;
        } else {
            // region overflow (P ~ 1e-9): exact accumulate via global atomics
            unsigned snd = rc.x & 0x1FFFFu;
            unsigned rl = rc.x >> 17;
            float ev = __uint_as_float(rc.y);
            const float4* qs = reinterpret_cast<const float4*>(qT + (size_t)snd * NF);
            float4 q0 = qs[0];
            float4 q1 = qs[1];
            float* a = govf + ((size_t)bkt * BNODES + rl) * 9;
            atomicAdd(a + 0, q0.x); atomicAdd(a + 1, q0.y);
            atomicAdd(a + 2, q0.z); atomicAdd(a + 3, q0.w);
            atomicAdd(a + 4, q1.x); atomicAdd(a + 5, q1.y);
            atomicAdd(a + 6, q1.z); atomicAdd(a + 7, q1.w);
            atomicAdd(a + 8, ev);
        }
    }
}

// P2: slot-scatter reduce (R8 structure, best measured). LDS-resident slice,
// 1 LDS atomic/edge, per-node slot lists, 2 threads/node parity split.
__global__ __launch_bounds__(TPR) void k_reduce_slot(
        const uint2* __restrict__ rec, const unsigned* __restrict__ gcur,
        const float* __restrict__ qT, float* __restrict__ part,
        float* __restrict__ govf, int n_nodes) {
    __shared__ uint2 lrec[LSLICE];                   // 20 KB (reused as scratch)
    __shared__ unsigned short idx[BNODES * IDXSTR];  // 13.3 KB
    __shared__ unsigned cur[BNODES];                 // 1 KB
    int t = threadIdx.x;
    if (t < BNODES) cur[t] = 0;
    __syncthreads();

    int bkt = blockIdx.x / SPLIT;
    int s   = blockIdx.x % SPLIT;
    unsigned len = gcur[bkt];
    if (len > CAPB) len = CAPB;
    size_t base = (size_t)bkt * CAPB;
    unsigned a0 = (unsigned)(((unsigned long long)len * s) / SPLIT);
    unsigned a1 = (unsigned)(((unsigned long long)len * (s + 1)) / SPLIT);
    unsigned slice = a1 - a0;

    // pass 1: stream slice into LDS, slot-scatter indices (1 LDS atomic/edge)
    for (unsigned i = t; i < slice; i += TPR) {
        uint2 rc = rec[base + a0 + i];
        if (i < LSLICE) lrec[i] = rc;
        unsigned rl = rc.x >> 17;
        unsigned pos = atomicAdd(&cur[rl], 1u);
        if (pos < CAP) {
            idx[rl * IDXSTR + pos] = (unsigned short)i;
        } else {
            // rare overflow: accumulate exactly via global atomics
            unsigned snd = rc.x & 0x1FFFFu;
            float ev = __uint_as_float(rc.y);
            const float4* qs = reinterpret_cast<const float4*>(qT + (size_t)snd * NF);
            float4 q0 = qs[0];
            float4 q1 = qs[1];
            float* a = govf + ((size_t)bkt * BNODES + rl) * 9;
            atomicAdd(a + 0, q0.x); atomicAdd(a + 1, q0.y);
            atomicAdd(a + 2, q0.z); atomicAdd(a + 3, q0.w);
            atomicAdd(a + 4, q1.x); atomicAdd(a + 5, q1.y);
            atomicAdd(a + 6, q1.z); atomicAdd(a + 7, q1.w);
            atomicAdd(a + 8, ev);
        }
    }
    __syncthreads();

    // pass 2: threads (2n, 2n+1) own node n; parity-split slot list.
    int node = t >> 1;
    int parity = t & 1;
    float m[9];
#pragma unroll
    for (int k = 0; k < 9; ++k) m[k] = 0.f;
    unsigned cntv = cur[node];
    if (cntv > CAP) cntv = CAP;
    for (unsigned j = parity; j < cntv; j += 2) {
        unsigned i0 = idx[node * IDXSTR + j];
        uint2 rc0 = (i0 < LSLICE) ? lrec[i0] : rec[base + a0 + i0];
        const float4* qs0 = reinterpret_cast<const float4*>(qT + (size_t)(rc0.x & 0x1FFFFu) * NF);
        float4 a0v = qs0[0], a1v = qs0[1];
        m[0] += a0v.x; m[1] += a0v.y; m[2] += a0v.z; m[3] += a0v.w;
        m[4] += a1v.x; m[5] += a1v.y; m[6] += a1v.z; m[7] += a1v.w;
        m[8] += __uint_as_float(rc0.y);
    }
    __syncthreads();   // all lrec reads done; safe to reuse as scratch

    float* scratch = reinterpret_cast<float*>(lrec);  // 256*9 floats = 9 KB
    if (parity == 1) {
        float* d = scratch + (size_t)node * 9;
#pragma unroll
        for (int k = 0; k < 9; ++k) d[k] = m[k];
    }
    __syncthreads();
    if (parity == 0) {
        const float* p2 = scratch + (size_t)node * 9;
        float* dst = part + (size_t)blockIdx.x * (BNODES * 9) + (size_t)node * 9;
#pragma unroll
        for (int k = 0; k < 9; ++k) dst[k] = m[k] + p2[k];
    }
}

// P3: sum SPLIT partials per node (+ global overflow), fused finalize.
__global__ void k_finalize2(const float* __restrict__ part, const float* __restrict__ govf,
                            const float* __restrict__ q,
                            const float* __restrict__ dtp, const float* __restrict__ w_self,
                            const float* __restrict__ w_msg, const float* __restrict__ w_edge,
                            const float* __restrict__ bv, float* __restrict__ out,
                            int split, int n_nodes) {
    int n = blockIdx.x * blockDim.x + threadIdx.x;
    if (n >= n_nodes) return;
    int bkt = n >> BSHIFT;
    int rl = n & (BNODES - 1);
    float m[9];
#pragma unroll
    for (int f = 0; f < 9; ++f) m[f] = govf[(size_t)n * 9 + f];
    for (int s = 0; s < split; ++s) {
        const float* p = part + ((size_t)(bkt * split + s) * BNODES + rl) * 9;
#pragma unroll
        for (int f = 0; f < 9; ++f) m[f] += p[f];
    }
    float dtv = dtp[0];
    float evs = m[8];
#pragma unroll
    for (int f = 0; f < NF; ++f) {
        float msg = m[f] + w_edge[f] * evs;
        out[(size_t)f * n_nodes + n] =
            dtv * (w_self[f] * q[(size_t)f * n_nodes + n] + w_msg[f] * msg + bv[f]);
    }
}

// ---------- last-resort fallback (global atomics) ----------
__global__ void k_transpose_zero(const float* __restrict__ q, float* __restrict__ qT,
                                 float* __restrict__ msgT, int n_nodes) {
    int n = blockIdx.x * blockDim.x + threadIdx.x;
    if (n >= n_nodes) return;
    float v[NF];
#pragma unroll
    for (int f = 0; f < NF; ++f) v[f] = q[f * n_nodes + n];
    float4* dst = reinterpret_cast<float4*>(qT + (size_t)n * NF);
    dst[0] = make_float4(v[0], v[1], v[2], v[3]);
    dst[1] = make_float4(v[4], v[5], v[6], v[7]);
    float4 z = make_float4(0.f, 0.f, 0.f, 0.f);
    float4* m = reinterpret_cast<float4*>(msgT + (size_t)n * NF);
    m[0] = z; m[1] = z;
}

__global__ void k_edge_scatter(const float* __restrict__ edges, const int* __restrict__ senders,
                               const int* __restrict__ receivers, const float* __restrict__ qT,
                               float* __restrict__ msgT, const float* __restrict__ w_edge,
                               int n_edges) {
    float we[NF];
#pragma unroll
    for (int f = 0; f < NF; ++f) we[f] = w_edge[f];
    int idx = blockIdx.x * blockDim.x + threadIdx.x;
    int stride = gridDim.x * blockDim.x;
    for (int e = idx; e < n_edges; e += stride) {
        int s = senders[e];
        int r = receivers[e];
        float ev = edges[e];
        const float4* qs = reinterpret_cast<const float4*>(qT + (size_t)s * NF);
        float4 q0 = qs[0];
        float4 q1 = qs[1];
        float* m = msgT + (size_t)r * NF;
        atomicAdd(m + 0, q0.x + we[0] * ev);
        atomicAdd(m + 1, q0.y + we[1] * ev);
        atomicAdd(m + 2, q0.z + we[2] * ev);
        atomicAdd(m + 3, q0.w + we[3] * ev);
        atomicAdd(m + 4, q1.x + we[4] * ev);
        atomicAdd(m + 5, q1.y + we[5] * ev);
        atomicAdd(m + 6, q1.z + we[6] * ev);
        atomicAdd(m + 7, q1.w + we[7] * ev);
    }
}

__global__ void k_finalize(const float* __restrict__ q, const float* __restrict__ msgT,
                           const float* __restrict__ dt, const float* __restrict__ w_self,
                           const float* __restrict__ w_msg, const float* __restrict__ b,
                           float* __restrict__ out, int n_nodes) {
    int n = blockIdx.x * blockDim.x + threadIdx.x;
    if (n >= n_nodes) return;
    float dtv = dt[0];
    const float4* m4 = reinterpret_cast<const float4*>(msgT + (size_t)n * NF);
    float4 m0 = m4[0];
    float4 m1 = m4[1];
    float mv[NF] = {m0.x, m0.y, m0.z, m0.w, m1.x, m1.y, m1.z, m1.w};
#pragma unroll
    for (int f = 0; f < NF; ++f) {
        out[f * n_nodes + n] = dtv * (w_self[f] * q[f * n_nodes + n] + w_msg[f] * mv[f] + b[f]);
    }
}

// ---------------- launch ----------------
extern "C" void kernel_launch(void* const* d_in, const int* in_sizes, int n_in,
                              void* d_out, int out_size, void* d_ws, size_t ws_size,
                              hipStream_t stream) {
    const float* q         = (const float*)d_in[0];
    const float* edges     = (const float*)d_in[1];
    const int*   senders   = (const int*)d_in[2];
    const int*   receivers = (const int*)d_in[3];
    const float* dt        = (const float*)d_in[4];
    const float* w_self    = (const float*)d_in[5];
    const float* w_msg     = (const float*)d_in[6];
    const float* w_edge    = (const float*)d_in[7];
    const float* b         = (const float*)d_in[8];
    float* out = (float*)d_out;

    const int n_nodes = in_sizes[0] / NF;   // 100000
    const int n_edges = in_sizes[2];        // 6400000
    const int nb = (n_nodes + BNODES - 1) >> BSHIFT;

    size_t rec_bytes  = (size_t)nb * CAPB * 8;
    size_t qT_bytes   = (size_t)n_nodes * NF * 4;
    size_t gcur_bytes = 256 + (size_t)nb * 4;           // padded
    size_t govf_bytes = (size_t)nb * BNODES * 9 * 4;
    size_t part_bytes = (size_t)SPLIT * nb * BNODES * 9 * 4;
    size_t need = rec_bytes + qT_bytes + gcur_bytes + govf_bytes + part_bytes + 1024;

    // mean bucket load must be comfortably under CAPB (8+ sigma margin)
    double mean_per_bucket = (double)n_edges / (double)nb;
    bool ok = (n_nodes <= 131072) && (nb <= MAXNB) && (need <= ws_size) &&
              (mean_per_bucket + 8.0 * __builtin_sqrt(mean_per_bucket) < (double)CAPB);

    if (ok) {
        char* p = (char*)d_ws;
        uint2*    rec  = (uint2*)p;    p += rec_bytes;
        float*    qT   = (float*)p;    p += qT_bytes;
        unsigned* gcur = (unsigned*)p; p += gcur_bytes;
        float*    govf = (float*)p;    p += govf_bytes;
        float*    part = (float*)(((uintptr_t)p + 255) & ~(uintptr_t)255);

        int nblk_f = (n_edges + CHUNKF - 1) / CHUNKF;

        k_transpose<<<(n_nodes + TPB - 1) / TPB, TPB, 0, stream>>>(q, qT, govf, gcur,
                                                                   n_nodes, nb);
        k_scatter_fused<<<nblk_f, TPBF, 0, stream>>>(edges, senders, receivers, n_edges,
                                                     nb, gcur, qT, govf, rec);
        k_reduce_slot<<<nb * SPLIT, TPR, 0, stream>>>(rec, gcur, qT, part, govf, n_nodes);
        k_finalize2<<<(n_nodes + TPB - 1) / TPB, TPB, 0, stream>>>(
            part, govf, q, dt, w_self, w_msg, w_edge, b, out, SPLIT, n_nodes);
    } else {
        float* qT   = (float*)d_ws;
        float* msgT = qT + (size_t)n_nodes * NF;
        k_transpose_zero<<<(n_nodes + TPB - 1) / TPB, TPB, 0, stream>>>(q, qT, msgT, n_nodes);
        k_edge_scatter<<<3072, TPB, 0, stream>>>(edges, senders, receivers, qT, msgT,
                                                 w_edge, n_edges);
        k_finalize<<<(n_nodes + TPB - 1) / TPB, TPB, 0, stream>>>(q, msgT, dt, w_self, w_msg,
                                                                  b, out, n_nodes);
    }
}

// Round 12
// 110.329 us; speedup vs baseline: 1.2357x; 1.0084x over previous
//
#include <hip/hip_runtime.h>

#define NF 8
#define BSHIFT 8
#define BNODES 256          // nodes per bucket = 1 << BSHIFT
#define MAXNB 512           // max buckets supported (n_nodes <= 131072)
#define TPB 256
#define TPR 512             // threads for reduce (2 per node)
#define TPBF 1024           // threads for fused scatter
#define CHUNKF 6144         // edges per sort tile (68 KB LDS -> 2 blocks/CU)
#define NBLKF 512           // persistent grid for fused scatter
#define CAPB 17408          // per-bucket region capacity (mean 16368 + 8 sigma)
#define SPLIT 8             // slices per bucket (slice ~2048 records)
#define CAP 24              // slots per node per block-slice
#define IDXSTR 26           // padded stride -> conflict-free u16 reads
#define LSLICE 2560         // LDS-resident slice capacity (records)

// P0: transpose q[f][n] -> qT[n][f]; zero govf and the global bucket cursors.
__global__ void k_transpose(const float* __restrict__ q, float* __restrict__ qT,
                            float* __restrict__ govf, unsigned* __restrict__ gcur,
                            int n_nodes, int nb) {
    int n = blockIdx.x * blockDim.x + threadIdx.x;
    if (n < nb) gcur[n] = 0u;
    if (n >= n_nodes) return;
    float4 a, b;
    a.x = q[0 * n_nodes + n]; a.y = q[1 * n_nodes + n];
    a.z = q[2 * n_nodes + n]; a.w = q[3 * n_nodes + n];
    b.x = q[4 * n_nodes + n]; b.y = q[5 * n_nodes + n];
    b.z = q[6 * n_nodes + n]; b.w = q[7 * n_nodes + n];
    float4* dst = reinterpret_cast<float4*>(qT + (size_t)n * NF);
    dst[0] = a; dst[1] = b;
    float* o = govf + (size_t)n * 9;
#pragma unroll
    for (int k = 0; k < 9; ++k) o[k] = 0.f;
}

// P1 (fused, persistent grid): per tile {LDS hist -> global reservation ->
// LDS counting sort -> run-coalesced write-out into fixed-capacity regions}.
__global__ __launch_bounds__(TPBF) void k_scatter_fused(
        const float* __restrict__ edges, const int* __restrict__ senders,
        const int* __restrict__ receivers, int n_edges, int nb, int tiles,
        unsigned* __restrict__ gcur, const float* __restrict__ qT,
        float* __restrict__ govf, uint2* __restrict__ rec) {
    __shared__ uint2 lrec[CHUNKF];            // 48 KB
    __shared__ unsigned short lbkt[CHUNKF];   // 12 KB
    __shared__ unsigned hist[MAXNB];          // 2 KB
    __shared__ unsigned lbase[MAXNB];         // 2 KB
    __shared__ unsigned gbase[MAXNB];         // 2 KB
    __shared__ unsigned lcur[MAXNB];          // 2 KB

    for (int t = blockIdx.x; t < tiles; t += gridDim.x) {
        int start = t * CHUNKF;
        int end = min(start + CHUNKF, n_edges);
        int n = end - start;

        for (int i = threadIdx.x; i < nb; i += TPBF) { hist[i] = 0u; lcur[i] = 0u; }
        __syncthreads();

        // pass A: histogram this tile (receivers stream; stays hot in L2)
        for (int i = threadIdx.x; i < n; i += TPBF)
            atomicAdd(&hist[receivers[start + i] >> BSHIFT], 1u);
        __syncthreads();

        // reserve region space per bucket (global atomic, L2-resident counters)
        if (threadIdx.x < (unsigned)nb)
            gbase[threadIdx.x] = atomicAdd(&gcur[threadIdx.x], hist[threadIdx.x]);
        // wave 0: exclusive scan of hist -> lbase (chunks of 64 with carry)
        if (threadIdx.x < 64) {
            int lane = threadIdx.x;
            unsigned carry = 0;
            for (int base = 0; base < nb; base += 64) {
                int bi = base + lane;
                unsigned v = (bi < nb) ? hist[bi] : 0u;
                unsigned x = v;
                for (int d = 1; d < 64; d <<= 1) {
                    unsigned y = __shfl_up(x, d, 64);
                    if (lane >= d) x += y;
                }
                if (bi < nb) lbase[bi] = carry + x - v;
                carry += __shfl(x, 63, 64);
            }
        }
        __syncthreads();

        // pass B: place into tile-local sorted LDS position (re-reads from L2)
        for (int i = threadIdx.x; i < n; i += TPBF) {
            int e = start + i;
            int s = senders[e];
            int r = receivers[e];
            float ev = edges[e];
            int bkt = r >> BSHIFT;
            unsigned p = atomicAdd(&lcur[bkt], 1u);
            unsigned slot = lbase[bkt] + p;
            uint2 rc;
            rc.x = ((unsigned)(r & (BNODES - 1)) << 17) | (unsigned)s;
            rc.y = __float_as_uint(ev);
            lrec[slot] = rc;
            lbkt[slot] = (unsigned short)bkt;
        }
        __syncthreads();

        // write-out: consecutive threads -> consecutive addresses per run
        for (int j = threadIdx.x; j < n; j += TPBF) {
            unsigned bkt = lbkt[j];
            uint2 rc = lrec[j];
            unsigned off = gbase[bkt] + ((unsigned)j - lbase[bkt]);
            if (off < CAPB) {
                rec[(size_t)bkt * CAPB + off] = rc;
            } else {
                // region overflow (P ~ 1e-9): exact accumulate via global atomics
                unsigned snd = rc.x & 0x1FFFFu;
                unsigned rl = rc.x >> 17;
                float ev = __uint_as_float(rc.y);
                const float4* qs = reinterpret_cast<const float4*>(qT + (size_t)snd * NF);
                float4 q0 = qs[0];
                float4 q1 = qs[1];
                float* a = govf + ((size_t)bkt * BNODES + rl) * 9;
                atomicAdd(a + 0, q0.x); atomicAdd(a + 1, q0.y);
                atomicAdd(a + 2, q0.z); atomicAdd(a + 3, q0.w);
                atomicAdd(a + 4, q1.x); atomicAdd(a + 5, q1.y);
                atomicAdd(a + 6, q1.z); atomicAdd(a + 7, q1.w);
                atomicAdd(a + 8, ev);
            }
        }
        __syncthreads();
    }
}

// P2: slot-scatter reduce (R8 structure, best measured). LDS-resident slice,
// 1 LDS atomic/edge, per-node slot lists, 2 threads/node parity split.
__global__ __launch_bounds__(TPR) void k_reduce_slot(
        const uint2* __restrict__ rec, const unsigned* __restrict__ gcur,
        const float* __restrict__ qT, float* __restrict__ part,
        float* __restrict__ govf, int n_nodes) {
    __shared__ uint2 lrec[LSLICE];                   // 20 KB (reused as scratch)
    __shared__ unsigned short idx[BNODES * IDXSTR];  // 13.3 KB
    __shared__ unsigned cur[BNODES];                 // 1 KB
    int t = threadIdx.x;
    if (t < BNODES) cur[t] = 0;
    __syncthreads();

    int bkt = blockIdx.x / SPLIT;
    int s   = blockIdx.x % SPLIT;
    unsigned len = gcur[bkt];
    if (len > CAPB) len = CAPB;
    size_t base = (size_t)bkt * CAPB;
    unsigned a0 = (unsigned)(((unsigned long long)len * s) / SPLIT);
    unsigned a1 = (unsigned)(((unsigned long long)len * (s + 1)) / SPLIT);
    unsigned slice = a1 - a0;

    // pass 1: stream slice into LDS, slot-scatter indices (1 LDS atomic/edge)
    for (unsigned i = t; i < slice; i += TPR) {
        uint2 rc = rec[base + a0 + i];
        if (i < LSLICE) lrec[i] = rc;
        unsigned rl = rc.x >> 17;
        unsigned pos = atomicAdd(&cur[rl], 1u);
        if (pos < CAP) {
            idx[rl * IDXSTR + pos] = (unsigned short)i;
        } else {
            // rare overflow: accumulate exactly via global atomics
            unsigned snd = rc.x & 0x1FFFFu;
            float ev = __uint_as_float(rc.y);
            const float4* qs = reinterpret_cast<const float4*>(qT + (size_t)snd * NF);
            float4 q0 = qs[0];
            float4 q1 = qs[1];
            float* a = govf + ((size_t)bkt * BNODES + rl) * 9;
            atomicAdd(a + 0, q0.x); atomicAdd(a + 1, q0.y);
            atomicAdd(a + 2, q0.z); atomicAdd(a + 3, q0.w);
            atomicAdd(a + 4, q1.x); atomicAdd(a + 5, q1.y);
            atomicAdd(a + 6, q1.z); atomicAdd(a + 7, q1.w);
            atomicAdd(a + 8, ev);
        }
    }
    __syncthreads();

    // pass 2: threads (2n, 2n+1) own node n; parity-split slot list.
    int node = t >> 1;
    int parity = t & 1;
    float m[9];
#pragma unroll
    for (int k = 0; k < 9; ++k) m[k] = 0.f;
    unsigned cntv = cur[node];
    if (cntv > CAP) cntv = CAP;
    for (unsigned j = parity; j < cntv; j += 2) {
        unsigned i0 = idx[node * IDXSTR + j];
        uint2 rc0 = (i0 < LSLICE) ? lrec[i0] : rec[base + a0 + i0];
        const float4* qs0 = reinterpret_cast<const float4*>(qT + (size_t)(rc0.x & 0x1FFFFu) * NF);
        float4 a0v = qs0[0], a1v = qs0[1];
        m[0] += a0v.x; m[1] += a0v.y; m[2] += a0v.z; m[3] += a0v.w;
        m[4] += a1v.x; m[5] += a1v.y; m[6] += a1v.z; m[7] += a1v.w;
        m[8] += __uint_as_float(rc0.y);
    }
    __syncthreads();   // all lrec reads done; safe to reuse as scratch

    float* scratch = reinterpret_cast<float*>(lrec);  // 256*9 floats = 9 KB
    if (parity == 1) {
        float* d = scratch + (size_t)node * 9;
#pragma unroll
        for (int k = 0; k < 9; ++k) d[k] = m[k];
    }
    __syncthreads();
    if (parity == 0) {
        const float* p2 = scratch + (size_t)node * 9;
        float* dst = part + (size_t)blockIdx.x * (BNODES * 9) + (size_t)node * 9;
#pragma unroll
        for (int k = 0; k < 9; ++k) dst[k] = m[k] + p2[k];
    }
}

// P3: sum SPLIT partials per node (+ global overflow), fused finalize.
__global__ void k_finalize2(const float* __restrict__ part, const float* __restrict__ govf,
                            const float* __restrict__ q,
                            const float* __restrict__ dtp, const float* __restrict__ w_self,
                            const float* __restrict__ w_msg, const float* __restrict__ w_edge,
                            const float* __restrict__ bv, float* __restrict__ out,
                            int split, int n_nodes) {
    int n = blockIdx.x * blockDim.x + threadIdx.x;
    if (n >= n_nodes) return;
    int bkt = n >> BSHIFT;
    int rl = n & (BNODES - 1);
    float m[9];
#pragma unroll
    for (int f = 0; f < 9; ++f) m[f] = govf[(size_t)n * 9 + f];
    for (int s = 0; s < split; ++s) {
        const float* p = part + ((size_t)(bkt * split + s) * BNODES + rl) * 9;
#pragma unroll
        for (int f = 0; f < 9; ++f) m[f] += p[f];
    }
    float dtv = dtp[0];
    float evs = m[8];
#pragma unroll
    for (int f = 0; f < NF; ++f) {
        float msg = m[f] + w_edge[f] * evs;
        out[(size_t)f * n_nodes + n] =
            dtv * (w_self[f] * q[(size_t)f * n_nodes + n] + w_msg[f] * msg + bv[f]);
    }
}

// ---------- last-resort fallback (global atomics) ----------
__global__ void k_transpose_zero(const float* __restrict__ q, float* __restrict__ qT,
                                 float* __restrict__ msgT, int n_nodes) {
    int n = blockIdx.x * blockDim.x + threadIdx.x;
    if (n >= n_nodes) return;
    float v[NF];
#pragma unroll
    for (int f = 0; f < NF; ++f) v[f] = q[f * n_nodes + n];
    float4* dst = reinterpret_cast<float4*>(qT + (size_t)n * NF);
    dst[0] = make_float4(v[0], v[1], v[2], v[3]);
    dst[1] = make_float4(v[4], v[5], v[6], v[7]);
    float4 z = make_float4(0.f, 0.f, 0.f, 0.f);
    float4* m = reinterpret_cast<float4*>(msgT + (size_t)n * NF);
    m[0] = z; m[1] = z;
}

__global__ void k_edge_scatter(const float* __restrict__ edges, const int* __restrict__ senders,
                               const int* __restrict__ receivers, const float* __restrict__ qT,
                               float* __restrict__ msgT, const float* __restrict__ w_edge,
                               int n_edges) {
    float we[NF];
#pragma unroll
    for (int f = 0; f < NF; ++f) we[f] = w_edge[f];
    int idx = blockIdx.x * blockDim.x + threadIdx.x;
    int stride = gridDim.x * blockDim.x;
    for (int e = idx; e < n_edges; e += stride) {
        int s = senders[e];
        int r = receivers[e];
        float ev = edges[e];
        const float4* qs = reinterpret_cast<const float4*>(qT + (size_t)s * NF);
        float4 q0 = qs[0];
        float4 q1 = qs[1];
        float* m = msgT + (size_t)r * NF;
        atomicAdd(m + 0, q0.x + we[0] * ev);
        atomicAdd(m + 1, q0.y + we[1] * ev);
        atomicAdd(m + 2, q0.z + we[2] * ev);
        atomicAdd(m + 3, q0.w + we[3] * ev);
        atomicAdd(m + 4, q1.x + we[4] * ev);
        atomicAdd(m + 5, q1.y + we[5] * ev);
        atomicAdd(m + 6, q1.z + we[6] * ev);
        atomicAdd(m + 7, q1.w + we[7] * ev);
    }
}

__global__ void k_finalize(const float* __restrict__ q, const float* __restrict__ msgT,
                           const float* __restrict__ dt, const float* __restrict__ w_self,
                           const float* __restrict__ w_msg, const float* __restrict__ b,
                           float* __restrict__ out, int n_nodes) {
    int n = blockIdx.x * blockDim.x + threadIdx.x;
    if (n >= n_nodes) return;
    float dtv = dt[0];
    const float4* m4 = reinterpret_cast<const float4*>(msgT + (size_t)n * NF);
    float4 m0 = m4[0];
    float4 m1 = m4[1];
    float mv[NF] = {m0.x, m0.y, m0.z, m0.w, m1.x, m1.y, m1.z, m1.w};
#pragma unroll
    for (int f = 0; f < NF; ++f) {
        out[f * n_nodes + n] = dtv * (w_self[f] * q[f * n_nodes + n] + w_msg[f] * mv[f] + b[f]);
    }
}

// ---------------- launch ----------------
extern "C" void kernel_launch(void* const* d_in, const int* in_sizes, int n_in,
                              void* d_out, int out_size, void* d_ws, size_t ws_size,
                              hipStream_t stream) {
    const float* q         = (const float*)d_in[0];
    const float* edges     = (const float*)d_in[1];
    const int*   senders   = (const int*)d_in[2];
    const int*   receivers = (const int*)d_in[3];
    const float* dt        = (const float*)d_in[4];
    const float* w_self    = (const float*)d_in[5];
    const float* w_msg     = (const float*)d_in[6];
    const float* w_edge    = (const float*)d_in[7];
    const float* b         = (const float*)d_in[8];
    float* out = (float*)d_out;

    const int n_nodes = in_sizes[0] / NF;   // 100000
    const int n_edges = in_sizes[2];        // 6400000
    const int nb = (n_nodes + BNODES - 1) >> BSHIFT;
    const int tiles = (n_edges + CHUNKF - 1) / CHUNKF;

    size_t rec_bytes  = (size_t)nb * CAPB * 8;
    size_t qT_bytes   = (size_t)n_nodes * NF * 4;
    size_t gcur_bytes = 256 + (size_t)nb * 4;           // padded
    size_t govf_bytes = (size_t)nb * BNODES * 9 * 4;
    size_t part_bytes = (size_t)SPLIT * nb * BNODES * 9 * 4;
    size_t need = rec_bytes + qT_bytes + gcur_bytes + govf_bytes + part_bytes + 1024;

    // mean bucket load must be comfortably under CAPB (8+ sigma margin)
    double mean_per_bucket = (double)n_edges / (double)nb;
    bool ok = (n_nodes <= 131072) && (nb <= MAXNB) && (need <= ws_size) &&
              (mean_per_bucket + 8.0 * __builtin_sqrt(mean_per_bucket) < (double)CAPB);

    if (ok) {
        char* p = (char*)d_ws;
        uint2*    rec  = (uint2*)p;    p += rec_bytes;
        float*    qT   = (float*)p;    p += qT_bytes;
        unsigned* gcur = (unsigned*)p; p += gcur_bytes;
        float*    govf = (float*)p;    p += govf_bytes;
        float*    part = (float*)(((uintptr_t)p + 255) & ~(uintptr_t)255);

        int nblk_f = tiles < NBLKF ? tiles : NBLKF;

        k_transpose<<<(n_nodes + TPB - 1) / TPB, TPB, 0, stream>>>(q, qT, govf, gcur,
                                                                   n_nodes, nb);
        k_scatter_fused<<<nblk_f, TPBF, 0, stream>>>(edges, senders, receivers, n_edges,
                                                     nb, tiles, gcur, qT, govf, rec);
        k_reduce_slot<<<nb * SPLIT, TPR, 0, stream>>>(rec, gcur, qT, part, govf, n_nodes);
        k_finalize2<<<(n_nodes + TPB - 1) / TPB, TPB, 0, stream>>>(
            part, govf, q, dt, w_self, w_msg, w_edge, b, out, SPLIT, n_nodes);
    } else {
        float* qT   = (float*)d_ws;
        float* msgT = qT + (size_t)n_nodes * NF;
        k_transpose_zero<<<(n_nodes + TPB - 1) / TPB, TPB, 0, stream>>>(q, qT, msgT, n_nodes);
        k_edge_scatter<<<3072, TPB, 0, stream>>>(edges, senders, receivers, qT, msgT,
                                                 w_edge, n_edges);
        k_finalize<<<(n_nodes + TPB - 1) / TPB, TPB, 0, stream>>>(q, msgT, dt, w_self, w_msg,
                                                                  b, out, n_nodes);
    }
}

// Round 13
// 108.564 us; speedup vs baseline: 1.2558x; 1.0163x over previous
//
#include <hip/hip_runtime.h>

#define NF 8
#define BSHIFT 8
#define BNODES 256          // nodes per bucket = 1 << BSHIFT
#define MAXNB 512           // max buckets supported (n_nodes <= 131072)
#define TPB 256
#define TPR 512             // threads for reduce (2 per node)
#define TPBF 1024           // threads for fused scatter
#define CHUNKF 6144         // edges per sort tile (66 KB LDS -> 2 blocks/CU)
#define KPE 6               // CHUNKF / TPBF records per thread (in registers)
#define NBLKF 512           // persistent grid for fused scatter
#define CAPB 17408          // per-bucket region capacity (mean 16368 + 8 sigma)
#define SPLIT 8             // slices per bucket (slice ~2048 records)
#define CAP 24              // slots per node per block-slice
#define IDXSTR 26           // padded stride -> conflict-free u16 reads
#define LSLICE 2560         // LDS-resident slice capacity (records)

// P0: transpose q[f][n] -> qT[n][f]; zero govf and the global bucket cursors.
__global__ void k_transpose(const float* __restrict__ q, float* __restrict__ qT,
                            float* __restrict__ govf, unsigned* __restrict__ gcur,
                            int n_nodes, int nb) {
    int n = blockIdx.x * blockDim.x + threadIdx.x;
    if (n < nb) gcur[n] = 0u;
    if (n >= n_nodes) return;
    float4 a, b;
    a.x = q[0 * n_nodes + n]; a.y = q[1 * n_nodes + n];
    a.z = q[2 * n_nodes + n]; a.w = q[3 * n_nodes + n];
    b.x = q[4 * n_nodes + n]; b.y = q[5 * n_nodes + n];
    b.z = q[6 * n_nodes + n]; b.w = q[7 * n_nodes + n];
    float4* dst = reinterpret_cast<float4*>(qT + (size_t)n * NF);
    dst[0] = a; dst[1] = b;
    float* o = govf + (size_t)n * 9;
#pragma unroll
    for (int k = 0; k < 9; ++k) o[k] = 0.f;
}

// P1 (fused, persistent grid, register-held records): per tile
// {pass A: load 6 edges/thread to REGISTERS + single position-returning LDS
//  atomic -> global reservation + scan -> phase C: place from registers into
//  sorted LDS slots -> run-coalesced write-out}. No pass-B re-read.
__global__ __launch_bounds__(TPBF) void k_scatter_fused(
        const float* __restrict__ edges, const int* __restrict__ senders,
        const int* __restrict__ receivers, int n_edges, int nb, int tiles,
        unsigned* __restrict__ gcur, const float* __restrict__ qT,
        float* __restrict__ govf, uint2* __restrict__ rec) {
    __shared__ uint2 lrec[CHUNKF];            // 48 KB
    __shared__ unsigned short lbkt[CHUNKF];   // 12 KB
    __shared__ unsigned hist[MAXNB];          // 2 KB
    __shared__ unsigned lbase[MAXNB];         // 2 KB
    __shared__ unsigned gbase[MAXNB];         // 2 KB

    for (int t = blockIdx.x; t < tiles; t += gridDim.x) {
        int start = t * CHUNKF;
        int end = min(start + CHUNKF, n_edges);
        int n = end - start;

        for (int i = threadIdx.x; i < nb; i += TPBF) hist[i] = 0u;
        __syncthreads();

        // pass A: stream this thread's KPE edges into registers; ONE LDS atomic
        // per edge returns the tile-local position within its bucket.
        unsigned rcx[KPE], rcy[KPE], meta[KPE];   // meta = (pos<<9) | bkt
#pragma unroll
        for (int k = 0; k < KPE; ++k) {
            int i = (int)threadIdx.x + k * TPBF;
            meta[k] = 0xFFFFFFFFu;
            if (i < n) {
                int e = start + i;
                int s = senders[e];
                int r = receivers[e];
                float ev = edges[e];
                unsigned bkt = (unsigned)r >> BSHIFT;
                unsigned p = atomicAdd(&hist[bkt], 1u);
                rcx[k] = ((unsigned)(r & (BNODES - 1)) << 17) | (unsigned)s;
                rcy[k] = __float_as_uint(ev);
                meta[k] = (p << 9) | bkt;
            }
        }
        __syncthreads();

        // reserve region space per bucket (global atomic, L2-resident counters)
        if (threadIdx.x < (unsigned)nb)
            gbase[threadIdx.x] = atomicAdd(&gcur[threadIdx.x], hist[threadIdx.x]);
        // wave 0: exclusive scan of hist -> lbase (chunks of 64 with carry)
        if (threadIdx.x < 64) {
            int lane = threadIdx.x;
            unsigned carry = 0;
            for (int base = 0; base < nb; base += 64) {
                int bi = base + lane;
                unsigned v = (bi < nb) ? hist[bi] : 0u;
                unsigned x = v;
                for (int d = 1; d < 64; d <<= 1) {
                    unsigned y = __shfl_up(x, d, 64);
                    if (lane >= d) x += y;
                }
                if (bi < nb) lbase[bi] = carry + x - v;
                carry += __shfl(x, 63, 64);
            }
        }
        __syncthreads();

        // phase C: place register-held records at sorted LDS positions
#pragma unroll
        for (int k = 0; k < KPE; ++k) {
            if (meta[k] != 0xFFFFFFFFu) {
                unsigned bkt = meta[k] & 0x1FFu;
                unsigned p   = meta[k] >> 9;
                unsigned slot = lbase[bkt] + p;
                lrec[slot] = make_uint2(rcx[k], rcy[k]);
                lbkt[slot] = (unsigned short)bkt;
            }
        }
        __syncthreads();

        // write-out: consecutive threads -> consecutive addresses per run
        for (int j = threadIdx.x; j < n; j += TPBF) {
            unsigned bkt = lbkt[j];
            uint2 rc = lrec[j];
            unsigned off = gbase[bkt] + ((unsigned)j - lbase[bkt]);
            if (off < CAPB) {
                rec[(size_t)bkt * CAPB + off] = rc;
            } else {
                // region overflow (P ~ 1e-9): exact accumulate via global atomics
                unsigned snd = rc.x & 0x1FFFFu;
                unsigned rl = rc.x >> 17;
                float ev = __uint_as_float(rc.y);
                const float4* qs = reinterpret_cast<const float4*>(qT + (size_t)snd * NF);
                float4 q0 = qs[0];
                float4 q1 = qs[1];
                float* a = govf + ((size_t)bkt * BNODES + rl) * 9;
                atomicAdd(a + 0, q0.x); atomicAdd(a + 1, q0.y);
                atomicAdd(a + 2, q0.z); atomicAdd(a + 3, q0.w);
                atomicAdd(a + 4, q1.x); atomicAdd(a + 5, q1.y);
                atomicAdd(a + 6, q1.z); atomicAdd(a + 7, q1.w);
                atomicAdd(a + 8, ev);
            }
        }
        __syncthreads();
    }
}

// P2: slot-scatter reduce (R8 structure, best measured). LDS-resident slice,
// 1 LDS atomic/edge, per-node slot lists, 2 threads/node parity split.
__global__ __launch_bounds__(TPR) void k_reduce_slot(
        const uint2* __restrict__ rec, const unsigned* __restrict__ gcur,
        const float* __restrict__ qT, float* __restrict__ part,
        float* __restrict__ govf, int n_nodes) {
    __shared__ uint2 lrec[LSLICE];                   // 20 KB (reused as scratch)
    __shared__ unsigned short idx[BNODES * IDXSTR];  // 13.3 KB
    __shared__ unsigned cur[BNODES];                 // 1 KB
    int t = threadIdx.x;
    if (t < BNODES) cur[t] = 0;
    __syncthreads();

    int bkt = blockIdx.x / SPLIT;
    int s   = blockIdx.x % SPLIT;
    unsigned len = gcur[bkt];
    if (len > CAPB) len = CAPB;
    size_t base = (size_t)bkt * CAPB;
    unsigned a0 = (unsigned)(((unsigned long long)len * s) / SPLIT);
    unsigned a1 = (unsigned)(((unsigned long long)len * (s + 1)) / SPLIT);
    unsigned slice = a1 - a0;

    // pass 1: stream slice into LDS, slot-scatter indices (1 LDS atomic/edge)
    for (unsigned i = t; i < slice; i += TPR) {
        uint2 rc = rec[base + a0 + i];
        if (i < LSLICE) lrec[i] = rc;
        unsigned rl = rc.x >> 17;
        unsigned pos = atomicAdd(&cur[rl], 1u);
        if (pos < CAP) {
            idx[rl * IDXSTR + pos] = (unsigned short)i;
        } else {
            // rare overflow: accumulate exactly via global atomics
            unsigned snd = rc.x & 0x1FFFFu;
            float ev = __uint_as_float(rc.y);
            const float4* qs = reinterpret_cast<const float4*>(qT + (size_t)snd * NF);
            float4 q0 = qs[0];
            float4 q1 = qs[1];
            float* a = govf + ((size_t)bkt * BNODES + rl) * 9;
            atomicAdd(a + 0, q0.x); atomicAdd(a + 1, q0.y);
            atomicAdd(a + 2, q0.z); atomicAdd(a + 3, q0.w);
            atomicAdd(a + 4, q1.x); atomicAdd(a + 5, q1.y);
            atomicAdd(a + 6, q1.z); atomicAdd(a + 7, q1.w);
            atomicAdd(a + 8, ev);
        }
    }
    __syncthreads();

    // pass 2: threads (2n, 2n+1) own node n; parity-split slot list.
    int node = t >> 1;
    int parity = t & 1;
    float m[9];
#pragma unroll
    for (int k = 0; k < 9; ++k) m[k] = 0.f;
    unsigned cntv = cur[node];
    if (cntv > CAP) cntv = CAP;
    for (unsigned j = parity; j < cntv; j += 2) {
        unsigned i0 = idx[node * IDXSTR + j];
        uint2 rc0 = (i0 < LSLICE) ? lrec[i0] : rec[base + a0 + i0];
        const float4* qs0 = reinterpret_cast<const float4*>(qT + (size_t)(rc0.x & 0x1FFFFu) * NF);
        float4 a0v = qs0[0], a1v = qs0[1];
        m[0] += a0v.x; m[1] += a0v.y; m[2] += a0v.z; m[3] += a0v.w;
        m[4] += a1v.x; m[5] += a1v.y; m[6] += a1v.z; m[7] += a1v.w;
        m[8] += __uint_as_float(rc0.y);
    }
    __syncthreads();   // all lrec reads done; safe to reuse as scratch

    float* scratch = reinterpret_cast<float*>(lrec);  // 256*9 floats = 9 KB
    if (parity == 1) {
        float* d = scratch + (size_t)node * 9;
#pragma unroll
        for (int k = 0; k < 9; ++k) d[k] = m[k];
    }
    __syncthreads();
    if (parity == 0) {
        const float* p2 = scratch + (size_t)node * 9;
        float* dst = part + (size_t)blockIdx.x * (BNODES * 9) + (size_t)node * 9;
#pragma unroll
        for (int k = 0; k < 9; ++k) dst[k] = m[k] + p2[k];
    }
}

// P3: sum SPLIT partials per node (+ global overflow), fused finalize.
__global__ void k_finalize2(const float* __restrict__ part, const float* __restrict__ govf,
                            const float* __restrict__ q,
                            const float* __restrict__ dtp, const float* __restrict__ w_self,
                            const float* __restrict__ w_msg, const float* __restrict__ w_edge,
                            const float* __restrict__ bv, float* __restrict__ out,
                            int split, int n_nodes) {
    int n = blockIdx.x * blockDim.x + threadIdx.x;
    if (n >= n_nodes) return;
    int bkt = n >> BSHIFT;
    int rl = n & (BNODES - 1);
    float m[9];
#pragma unroll
    for (int f = 0; f < 9; ++f) m[f] = govf[(size_t)n * 9 + f];
    for (int s = 0; s < split; ++s) {
        const float* p = part + ((size_t)(bkt * split + s) * BNODES + rl) * 9;
#pragma unroll
        for (int f = 0; f < 9; ++f) m[f] += p[f];
    }
    float dtv = dtp[0];
    float evs = m[8];
#pragma unroll
    for (int f = 0; f < NF; ++f) {
        float msg = m[f] + w_edge[f] * evs;
        out[(size_t)f * n_nodes + n] =
            dtv * (w_self[f] * q[(size_t)f * n_nodes + n] + w_msg[f] * msg + bv[f]);
    }
}

// ---------- last-resort fallback (global atomics) ----------
__global__ void k_transpose_zero(const float* __restrict__ q, float* __restrict__ qT,
                                 float* __restrict__ msgT, int n_nodes) {
    int n = blockIdx.x * blockDim.x + threadIdx.x;
    if (n >= n_nodes) return;
    float v[NF];
#pragma unroll
    for (int f = 0; f < NF; ++f) v[f] = q[f * n_nodes + n];
    float4* dst = reinterpret_cast<float4*>(qT + (size_t)n * NF);
    dst[0] = make_float4(v[0], v[1], v[2], v[3]);
    dst[1] = make_float4(v[4], v[5], v[6], v[7]);
    float4 z = make_float4(0.f, 0.f, 0.f, 0.f);
    float4* m = reinterpret_cast<float4*>(msgT + (size_t)n * NF);
    m[0] = z; m[1] = z;
}

__global__ void k_edge_scatter(const float* __restrict__ edges, const int* __restrict__ senders,
                               const int* __restrict__ receivers, const float* __restrict__ qT,
                               float* __restrict__ msgT, const float* __restrict__ w_edge,
                               int n_edges) {
    float we[NF];
#pragma unroll
    for (int f = 0; f < NF; ++f) we[f] = w_edge[f];
    int idx = blockIdx.x * blockDim.x + threadIdx.x;
    int stride = gridDim.x * blockDim.x;
    for (int e = idx; e < n_edges; e += stride) {
        int s = senders[e];
        int r = receivers[e];
        float ev = edges[e];
        const float4* qs = reinterpret_cast<const float4*>(qT + (size_t)s * NF);
        float4 q0 = qs[0];
        float4 q1 = qs[1];
        float* m = msgT + (size_t)r * NF;
        atomicAdd(m + 0, q0.x + we[0] * ev);
        atomicAdd(m + 1, q0.y + we[1] * ev);
        atomicAdd(m + 2, q0.z + we[2] * ev);
        atomicAdd(m + 3, q0.w + we[3] * ev);
        atomicAdd(m + 4, q1.x + we[4] * ev);
        atomicAdd(m + 5, q1.y + we[5] * ev);
        atomicAdd(m + 6, q1.z + we[6] * ev);
        atomicAdd(m + 7, q1.w + we[7] * ev);
    }
}

__global__ void k_finalize(const float* __restrict__ q, const float* __restrict__ msgT,
                           const float* __restrict__ dt, const float* __restrict__ w_self,
                           const float* __restrict__ w_msg, const float* __restrict__ b,
                           float* __restrict__ out, int n_nodes) {
    int n = blockIdx.x * blockDim.x + threadIdx.x;
    if (n >= n_nodes) return;
    float dtv = dt[0];
    const float4* m4 = reinterpret_cast<const float4*>(msgT + (size_t)n * NF);
    float4 m0 = m4[0];
    float4 m1 = m4[1];
    float mv[NF] = {m0.x, m0.y, m0.z, m0.w, m1.x, m1.y, m1.z, m1.w};
#pragma unroll
    for (int f = 0; f < NF; ++f) {
        out[f * n_nodes + n] = dtv * (w_self[f] * q[f * n_nodes + n] + w_msg[f] * mv[f] + b[f]);
    }
}

// ---------------- launch ----------------
extern "C" void kernel_launch(void* const* d_in, const int* in_sizes, int n_in,
                              void* d_out, int out_size, void* d_ws, size_t ws_size,
                              hipStream_t stream) {
    const float* q         = (const float*)d_in[0];
    const float* edges     = (const float*)d_in[1];
    const int*   senders   = (const int*)d_in[2];
    const int*   receivers = (const int*)d_in[3];
    const float* dt        = (const float*)d_in[4];
    const float* w_self    = (const float*)d_in[5];
    const float* w_msg     = (const float*)d_in[6];
    const float* w_edge    = (const float*)d_in[7];
    const float* b         = (const float*)d_in[8];
    float* out = (float*)d_out;

    const int n_nodes = in_sizes[0] / NF;   // 100000
    const int n_edges = in_sizes[2];        // 6400000
    const int nb = (n_nodes + BNODES - 1) >> BSHIFT;
    const int tiles = (n_edges + CHUNKF - 1) / CHUNKF;

    size_t rec_bytes  = (size_t)nb * CAPB * 8;
    size_t qT_bytes   = (size_t)n_nodes * NF * 4;
    size_t gcur_bytes = 256 + (size_t)nb * 4;           // padded
    size_t govf_bytes = (size_t)nb * BNODES * 9 * 4;
    size_t part_bytes = (size_t)SPLIT * nb * BNODES * 9 * 4;
    size_t need = rec_bytes + qT_bytes + gcur_bytes + govf_bytes + part_bytes + 1024;

    // mean bucket load must be comfortably under CAPB (8+ sigma margin)
    double mean_per_bucket = (double)n_edges / (double)nb;
    bool ok = (n_nodes <= 131072) && (nb <= MAXNB) && (need <= ws_size) &&
              (mean_per_bucket + 8.0 * __builtin_sqrt(mean_per_bucket) < (double)CAPB);

    if (ok) {
        char* p = (char*)d_ws;
        uint2*    rec  = (uint2*)p;    p += rec_bytes;
        float*    qT   = (float*)p;    p += qT_bytes;
        unsigned* gcur = (unsigned*)p; p += gcur_bytes;
        float*    govf = (float*)p;    p += govf_bytes;
        float*    part = (float*)(((uintptr_t)p + 255) & ~(uintptr_t)255);

        int nblk_f = tiles < NBLKF ? tiles : NBLKF;

        k_transpose<<<(n_nodes + TPB - 1) / TPB, TPB, 0, stream>>>(q, qT, govf, gcur,
                                                                   n_nodes, nb);
        k_scatter_fused<<<nblk_f, TPBF, 0, stream>>>(edges, senders, receivers, n_edges,
                                                     nb, tiles, gcur, qT, govf, rec);
        k_reduce_slot<<<nb * SPLIT, TPR, 0, stream>>>(rec, gcur, qT, part, govf, n_nodes);
        k_finalize2<<<(n_nodes + TPB - 1) / TPB, TPB, 0, stream>>>(
            part, govf, q, dt, w_self, w_msg, w_edge, b, out, SPLIT, n_nodes);
    } else {
        float* qT   = (float*)d_ws;
        float* msgT = qT + (size_t)n_nodes * NF;
        k_transpose_zero<<<(n_nodes + TPB - 1) / TPB, TPB, 0, stream>>>(q, qT, msgT, n_nodes);
        k_edge_scatter<<<3072, TPB, 0, stream>>>(edges, senders, receivers, qT, msgT,
                                                 w_edge, n_edges);
        k_finalize<<<(n_nodes + TPB - 1) / TPB, TPB, 0, stream>>>(q, msgT, dt, w_self, w_msg,
                                                                  b, out, n_nodes);
    }
}